// Round 1
// baseline (721.574 us; speedup 1.0000x reference)
//
#include <hip/hip_runtime.h>
#include <hip/hip_bf16.h>
#include <stdint.h>

// ---- problem constants ----
#define B_ATOMS 8192
#define C_CH    128
#define L_DIM   16
#define E_EL    10
#define NK3     23
#define NK2     4
#define NTRI    136   // 16*17/2 upper-triangle pairs
#define KPAD    160   // K padded to multiple of 32 for 16x16x32 MFMA
#define KOCT    20    // 160/8 16B-octets per row in the packed ws layout
#define KS      192   // LDS k-stride (bf16 elems): room for XOR-octet swizzle (24 octets)
#define NCOL    384   // V columns: 368 (i*23+k) + 4 (U2 k2) + 12 zero pad
#define NHALF   192
#define VS      197   // V fp32 row stride (odd -> conflict-free-ish b32)

// ---- LDS layout (bytes) ----
#define BT_OFF  0                 // 192*192*2 = 73728
#define XX_OFF  73728             // 128*192*2 = 49152 -> 122880
#define V_OFF   0                 // fp32 128*197*4 = 100864 (overlays BT+XX after MFMA)
#define X_OFF   122880            // 128*18*2 = 4608 -> 127488
#define W3_OFF  127488            // 128*23*4 = 11776 -> 139264
#define W2_OFF  139264            // 128*4*4 = 2048 -> 141312
#define W1_OFF  141312            // 128*4 = 512 -> 141824
#define SMEM_BYTES 141824

typedef __attribute__((ext_vector_type(8))) short short8;
typedef __attribute__((ext_vector_type(4))) float f32x4;

struct TriLut { unsigned char p[NTRI]; unsigned char q[NTRI]; };
static constexpr TriLut make_lut() {
  TriLut t{};
  int idx = 0;
  for (int p = 0; p < 16; ++p)
    for (int q = p; q < 16; ++q) { t.p[idx] = (unsigned char)p; t.q[idx] = (unsigned char)q; ++idx; }
  return t;
}
__constant__ TriLut LUT = make_lut();

__device__ __forceinline__ unsigned short f2bf(float f) {
  union { float f; unsigned u; } v; v.f = f;
  unsigned r = v.u + 0x7fffu + ((v.u >> 16) & 1u);   // RNE
  return (unsigned short)(r >> 16);
}
__device__ __forceinline__ float bf2f(unsigned short h) {
  union { unsigned u; float f; } v; v.u = ((unsigned)h) << 16;
  return v.f;
}

// ---- setup: pack symmetrized B' [n=384][k=160] bf16 into workspace ----
__global__ void build_bt(const float* __restrict__ U2, const float* __restrict__ U3,
                         unsigned short* __restrict__ bt) {
  int gid = blockIdx.x * 256 + threadIdx.x;
  if (gid >= NCOL * KPAD) return;
  int n  = gid / KPAD;
  int kk = gid - n * KPAD;
  float val = 0.f;
  if (kk < NTRI && n < 372) {
    int p = LUT.p[kk], q = LUT.q[kk];
    if (n < 368) {
      int i = n / NK3, k3 = n - i * NK3;
      val = U3[((p * 16 + q) * 16 + i) * NK3 + k3];
      if (p != q) val += U3[((q * 16 + p) * 16 + i) * NK3 + k3];
    } else {
      int k2 = n - 368;
      val = U2[(p * 16 + q) * NK2 + k2];
      if (p != q) val += U2[(q * 16 + p) * NK2 + k2];
    }
  }
  bt[gid] = f2bf(val);
}

// epilogue dot over 96 columns with compile-time (i,k) decode
template <int N0>
__device__ __forceinline__ float dot_seg(const float* __restrict__ V96,
                                         const float* xi, const float* w3r, const float* w2r) {
  float s = 0.f;
#pragma unroll
  for (int jj = 0; jj < 96; ++jj) {
    const int n = N0 + jj;
    if (n < 368) {
      const int i = n / NK3, k = n - i * NK3;
      s += V96[jj] * (xi[i] * w3r[k]);
    } else if (n < 372) {
      s += V96[jj] * w2r[n - 368];
    }
  }
  return s;
}

__global__ __launch_bounds__(256, 1) void mace_main(
    const float* __restrict__ x, const float* __restrict__ y,
    const float* __restrict__ U1, const float* __restrict__ W1,
    const float* __restrict__ W2, const float* __restrict__ W3,
    const unsigned short* __restrict__ bt, float* __restrict__ out) {
  __shared__ __align__(16) char smem[SMEM_BYTES];
  const int t  = threadIdx.x;
  const int b  = blockIdx.y;
  const int bx = blockIdx.x;  // n-half: columns [bx*192, bx*192+192)

  // ---- P0: stage B'-half into LDS with XOR-octet swizzle ----
  {
    const uint4* src = (const uint4*)(bt + bx * NHALF * KPAD);
    for (int u = t; u < NHALF * KOCT; u += 256) {
      int n = u / KOCT, o = u - n * KOCT;
      int dsto = n * (KS / 8) + (o ^ (n & 7));
      *(uint4*)(smem + BT_OFF + dsto * 16) = src[u];
    }
  }
  // ---- P1: x -> LDS bf16; per-channel combined weights w3/w2/w1 -> LDS ----
  {
    const float4* x4 = (const float4*)(x + (size_t)b * C_CH * L_DIM);
    for (int o = t; o < C_CH * L_DIM / 4; o += 256) {
      float4 f = x4[o];
      int c = o >> 2, i0 = (o & 3) * 4;
      unsigned int* xr = (unsigned int*)((unsigned short*)(smem + X_OFF) + c * 18 + i0);
      xr[0] = (unsigned)f2bf(f.x) | ((unsigned)f2bf(f.y) << 16);
      xr[1] = (unsigned)f2bf(f.z) | ((unsigned)f2bf(f.w) << 16);
    }
    if (t < C_CH) {
      float w3a[NK3], w2a[NK2], w1a = 0.f;
#pragma unroll
      for (int k = 0; k < NK3; ++k) w3a[k] = 0.f;
#pragma unroll
      for (int k = 0; k < NK2; ++k) w2a[k] = 0.f;
      for (int e = 0; e < E_EL; ++e) {
        float ye = y[b * E_EL + e];
#pragma unroll
        for (int k = 0; k < NK3; ++k) w3a[k] += ye * W3[(e * NK3 + k) * C_CH + t];
#pragma unroll
        for (int k = 0; k < NK2; ++k) w2a[k] += ye * W2[(e * NK2 + k) * C_CH + t];
        w1a += ye * W1[e * C_CH + t];
      }
      float* w3l = (float*)(smem + W3_OFF);
#pragma unroll
      for (int k = 0; k < NK3; ++k) w3l[t * NK3 + k] = w3a[k];
      float* w2l = (float*)(smem + W2_OFF);
#pragma unroll
      for (int k = 0; k < NK2; ++k) w2l[t * NK2 + k] = w2a[k];
      ((float*)(smem + W1_OFF))[t] = w1a;
    }
  }
  __syncthreads();
  // ---- P2: build XX[c, 0..135] = x_p*x_q (bf16, swizzled), zero 136..159 ----
  {
    int c = t >> 1, half = t & 1;
    const unsigned short* xr = (const unsigned short*)(smem + X_OFF) + c * 18;
    float xf[16];
#pragma unroll
    for (int i = 0; i < 16; ++i) xf[i] = bf2f(xr[i]);
    unsigned short* xxp = (unsigned short*)(smem + XX_OFF);
    int idx = 0;
#pragma unroll
    for (int p = 0; p < 16; ++p) {
#pragma unroll
      for (int q = p; q < 16; ++q) {
        if ((idx < 68) == (half == 0)) {
          int o = idx >> 3, j = idx & 7;
          xxp[c * KS + ((o ^ (c & 7)) << 3) + j] = f2bf(xf[p] * xf[q]);
        }
        ++idx;
      }
    }
    if (half) {
#pragma unroll
      for (int kk = NTRI; kk < KPAD; ++kk) {
        int o = kk >> 3, j = kk & 7;
        xxp[c * KS + ((o ^ (c & 7)) << 3) + j] = 0;
      }
    }
  }
  __syncthreads();
  // ---- P3: MFMA GEMM  V[128 x 192] += XX[128 x 160] * B'[160 x 192] ----
  const int lane = t & 63, wid = t >> 6;
  const int quad = lane >> 4, l16 = lane & 15;
  const int wm = (wid >> 1) * 64, wn = (wid & 1) * 96;  // wave tile 64 x 96
  f32x4 acc[4][6];
#pragma unroll
  for (int mt = 0; mt < 4; ++mt)
#pragma unroll
    for (int nt = 0; nt < 6; ++nt) acc[mt][nt] = (f32x4){0.f, 0.f, 0.f, 0.f};
#pragma unroll
  for (int ks = 0; ks < 5; ++ks) {
    short8 af[4];
#pragma unroll
    for (int mt = 0; mt < 4; ++mt) {
      int row = wm + mt * 16 + l16;
      int oct = (ks * 4 + quad) ^ (row & 7);
      af[mt] = *(const short8*)(smem + XX_OFF + (row * KS + oct * 8) * 2);
    }
#pragma unroll
    for (int nt = 0; nt < 6; ++nt) {
      int rowb = wn + nt * 16 + l16;
      int oct = (ks * 4 + quad) ^ (rowb & 7);
      short8 bfr = *(const short8*)(smem + BT_OFF + (rowb * KS + oct * 8) * 2);
#pragma unroll
      for (int mt = 0; mt < 4; ++mt)
        acc[mt][nt] = __builtin_amdgcn_mfma_f32_16x16x32_bf16(af[mt], bfr, acc[mt][nt], 0, 0, 0);
    }
  }
  __syncthreads();
  // ---- P4: stage V (fp32) into LDS, overlaying dead BT/XX ----
  {
    float* V = (float*)(smem + V_OFF);
#pragma unroll
    for (int mt = 0; mt < 4; ++mt)
#pragma unroll
      for (int nt = 0; nt < 6; ++nt)
#pragma unroll
        for (int r = 0; r < 4; ++r) {
          int c  = wm + mt * 16 + quad * 4 + r;   // D row = m
          int nl = wn + nt * 16 + l16;            // D col = n
          V[c * VS + nl] = acc[mt][nt][r];
        }
  }
  __syncthreads();
  // ---- P5: epilogue: out[b,c] += sum_n V[c,n]*O[c,n]  (+U1 term once) ----
  {
    const float* V = (const float*)(smem + V_OFF);
    int c = t & 127, h = t >> 7;
    const unsigned short* xr = (const unsigned short*)(smem + X_OFF) + c * 18;
    float xi[16];
#pragma unroll
    for (int i = 0; i < 16; ++i) xi[i] = bf2f(xr[i]);
    float w3r[NK3];
    const float* w3l = (const float*)(smem + W3_OFF) + c * NK3;
#pragma unroll
    for (int k = 0; k < NK3; ++k) w3r[k] = w3l[k];
    float w2r[NK2];
    const float* w2l = (const float*)(smem + W2_OFF) + c * NK2;
#pragma unroll
    for (int k = 0; k < NK2; ++k) w2r[k] = w2l[k];

    const float* V96 = V + c * VS + h * 96;
    int sel = bx * 2 + h;  // global n base = sel*96
    float partial;
    if (sel == 0)      partial = dot_seg<0>(V96, xi, w3r, w2r);
    else if (sel == 1) partial = dot_seg<96>(V96, xi, w3r, w2r);
    else if (sel == 2) partial = dot_seg<192>(V96, xi, w3r, w2r);
    else               partial = dot_seg<288>(V96, xi, w3r, w2r);

    if (sel == 0) {  // corr-1 term exactly once per (b,c)
      float S1 = 0.f;
#pragma unroll
      for (int p = 0; p < 16; ++p) S1 += U1[p] * xi[p];
      partial += ((const float*)(smem + W1_OFF))[c] * S1;
    }
    atomicAdd(&out[(size_t)b * C_CH + c], partial);
  }
}

extern "C" void kernel_launch(void* const* d_in, const int* in_sizes, int n_in,
                              void* d_out, int out_size, void* d_ws, size_t ws_size,
                              hipStream_t stream) {
  const float* x  = (const float*)d_in[0];
  const float* y  = (const float*)d_in[1];
  const float* U1 = (const float*)d_in[2];
  const float* U2 = (const float*)d_in[3];
  const float* U3 = (const float*)d_in[4];
  const float* W1 = (const float*)d_in[5];
  const float* W2 = (const float*)d_in[6];
  const float* W3 = (const float*)d_in[7];
  float* out = (float*)d_out;
  unsigned short* bt = (unsigned short*)d_ws;
  if (ws_size < (size_t)NCOL * KPAD * sizeof(unsigned short)) return;  // need 122,880 B scratch

  hipMemsetAsync(d_out, 0, (size_t)out_size * sizeof(float), stream);
  build_bt<<<dim3((NCOL * KPAD + 255) / 256), dim3(256), 0, stream>>>(U2, U3, bt);
  mace_main<<<dim3(2, B_ATOMS), dim3(256), 0, stream>>>(x, y, U1, W1, W2, W3, bt, out);
}

// Round 2
// 507.579 us; speedup vs baseline: 1.4216x; 1.4216x over previous
//
#include <hip/hip_runtime.h>
#include <hip/hip_bf16.h>
#include <stdint.h>

// ---- problem constants ----
#define B_ATOMS 8192
#define C_CH    128
#define L_DIM   16
#define E_EL    10
#define NK3     23
#define NK2     4
#define NTRI    136   // 16*17/2 upper-triangle pairs
#define KPAD    160   // K padded to 32-multiple for 16x16x32 MFMA
#define NCOL    384   // 368 (i*23+k3) + 4 (k2) + 12 zero pad
#define NQ      96    // columns per block (n-quarter)
#define KSB     336   // LDS k-stride in BYTES (168 bf16 elems; 336B = 20 banks mod 32 -> <=2-way b128)
#define VTS     136   // VT bf16 row stride (elems)

// ---- LDS layout (bytes) ----
#define BT_OFF  0                      // 96*336  = 32256
#define XX_OFF  32256                  // 128*336 = 43008 -> 75264
#define X_OFF   75264                  // 128*16*2 = 4096 -> 79360
#define VT_OFF  0                      // bf16 96*136*2 = 26112 (overlays dead BT)
#define SMEM_BYTES 79360               // x2 = 158720 <= 163840 -> 2 blocks/CU

typedef __attribute__((ext_vector_type(8))) short short8;
typedef __attribute__((ext_vector_type(4))) float f32x4;

struct TriLut { unsigned char p[NTRI]; unsigned char q[NTRI]; };
static constexpr TriLut make_lut() {
  TriLut t{};
  int idx = 0;
  for (int p = 0; p < 16; ++p)
    for (int q = p; q < 16; ++q) { t.p[idx] = (unsigned char)p; t.q[idx] = (unsigned char)q; ++idx; }
  return t;
}
__constant__ TriLut LUT = make_lut();

__device__ __forceinline__ unsigned short f2bf(float f) {
  union { float f; unsigned u; } v; v.f = f;
  unsigned r = v.u + 0x7fffu + ((v.u >> 16) & 1u);   // RNE
  return (unsigned short)(r >> 16);
}
__device__ __forceinline__ float bf2f(unsigned short h) {
  union { unsigned u; float f; } v; v.u = ((unsigned)h) << 16;
  return v.f;
}
__device__ __forceinline__ unsigned pack2(float a, float b) {
  __hip_bfloat162 h = __float22bfloat162_rn(float2{a, b});   // low half = a
  union { __hip_bfloat162 h; unsigned u; } v; v.h = h;
  return v.u;
}

// ---- setup: pack symmetrized B' [n=384][k=160] bf16 into workspace ----
__global__ void build_bt(const float* __restrict__ U2, const float* __restrict__ U3,
                         unsigned short* __restrict__ bt) {
  int gid = blockIdx.x * 256 + threadIdx.x;
  if (gid >= NCOL * KPAD) return;
  int n  = gid / KPAD;
  int kk = gid - n * KPAD;
  float val = 0.f;
  if (kk < NTRI && n < 372) {
    int p = LUT.p[kk], q = LUT.q[kk];
    if (n < 368) {
      int i = n / NK3, k3 = n - i * NK3;
      val = U3[((p * 16 + q) * 16 + i) * NK3 + k3];
      if (p != q) val += U3[((q * 16 + p) * 16 + i) * NK3 + k3];
    } else {
      int k2 = n - 368;
      val = U2[(p * 16 + q) * NK2 + k2];
      if (p != q) val += U2[(q * 16 + p) * NK2 + k2];
    }
  }
  bt[gid] = f2bf(val);
}

// epilogue: dot over this block's 96 columns, compile-time (i,k) decode,
// k-half partitioned across thread halves (w3 lives in registers).
template <int SEL>   // SEL = bx*2 + kh
__device__ __forceinline__ float epi_dot(const char* smem, int c, const float* xf,
                                         const float* w3r, const float* w2r) {
  constexpr int BX = SEL >> 1, KH = SEL & 1;
  const unsigned short* VTp = (const unsigned short*)(smem + VT_OFF) + c;
  float s = 0.f;
#pragma unroll
  for (int jj = 0; jj < NQ; ++jj) {
    const int n = BX * NQ + jj;
    if (n < 368) {
      const int i = n / NK3, k = n - (n / NK3) * NK3;
      if ((KH == 0) ? (k < 12) : (k >= 12)) {
        const float v = bf2f(VTp[jj * VTS]);
        s += v * xf[i] * w3r[k - (KH ? 12 : 0)];
      }
    } else if (n < 372) {
      if (KH == 0) s += bf2f(VTp[jj * VTS]) * w2r[n - 368];
    }
  }
  return s;
}

__global__ __launch_bounds__(256, 2) void mace_main(
    const float* __restrict__ x, const float* __restrict__ y,
    const float* __restrict__ U1, const float* __restrict__ W1,
    const float* __restrict__ W2, const float* __restrict__ W3,
    const unsigned short* __restrict__ bt, float* __restrict__ out) {
  __shared__ __align__(16) char smem[SMEM_BYTES];
  const int t  = threadIdx.x;
  const int b  = blockIdx.y;
  const int bx = blockIdx.x;  // n-quarter: columns [bx*96, bx*96+96)

  // ---- P0: stage B'-quarter into LDS (linear, stride 336B) ----
  {
    const uint4* src = (const uint4*)(bt + (size_t)bx * NQ * KPAD);
    for (int u = t; u < NQ * 20; u += 256) {
      int n = u / 20, o = u - n * 20;
      *(uint4*)(smem + BT_OFF + n * KSB + o * 16) = src[u];
    }
  }
  // ---- P1: x -> LDS bf16 ----
  {
    const float4* x4 = (const float4*)(x + (size_t)b * C_CH * L_DIM);
#pragma unroll
    for (int r = 0; r < 2; ++r) {
      int o = t + r * 256;
      float4 f = x4[o];
      int c = o >> 2, i0 = (o & 3) * 4;
      unsigned* dst = (unsigned*)((unsigned short*)(smem + X_OFF) + c * 16 + i0);
      dst[0] = pack2(f.x, f.y);
      dst[1] = pack2(f.z, f.w);
    }
  }
  // ---- P1b: combined per-channel weights -> REGISTERS (thread = (c, k-half)) ----
  const int ch = t & 127, kh = t >> 7;
  float w3r[12];
  float w2r[4] = {0.f, 0.f, 0.f, 0.f};
  float w1r = 0.f;
#pragma unroll
  for (int j = 0; j < 12; ++j) w3r[j] = 0.f;
  if (kh == 0) {
#pragma unroll
    for (int e = 0; e < E_EL; ++e) {
      const float ye = y[(size_t)b * E_EL + e];
#pragma unroll
      for (int j = 0; j < 12; ++j) w3r[j] += ye * W3[(e * NK3 + j) * C_CH + ch];
#pragma unroll
      for (int j = 0; j < 4; ++j) w2r[j] += ye * W2[(e * NK2 + j) * C_CH + ch];
      w1r += ye * W1[e * C_CH + ch];
    }
  } else {
#pragma unroll
    for (int e = 0; e < E_EL; ++e) {
      const float ye = y[(size_t)b * E_EL + e];
#pragma unroll
      for (int j = 0; j < 11; ++j) w3r[j] += ye * W3[(e * NK3 + 12 + j) * C_CH + ch];
    }
  }
  __syncthreads();
  // ---- P2: XX[c, k] = x_p*x_q bf16 (2 threads/row, packed pair writes) ----
  {
    const int c = t >> 1, half = t & 1;
    const unsigned short* xr = (const unsigned short*)(smem + X_OFF) + c * 16;
    short8 x0 = *(const short8*)(xr);
    short8 x1 = *(const short8*)(xr + 8);
    float xf[16];
#pragma unroll
    for (int i = 0; i < 8; ++i) {
      xf[i]     = bf2f((unsigned short)x0[i]);
      xf[i + 8] = bf2f((unsigned short)x1[i]);
    }
    unsigned* dst = (unsigned*)(smem + XX_OFF + c * KSB);
    float prev = 0.f;
    int idx = 0;
#pragma unroll
    for (int p = 0; p < 16; ++p) {
#pragma unroll
      for (int q = p; q < 16; ++q) {
        const bool mine = (idx < 68) == (half == 0);
        if (mine) {
          const float val = xf[p] * xf[q];
          if (idx & 1) dst[idx >> 1] = pack2(prev, val);
          else prev = val;
        }
        ++idx;
      }
    }
    if (half) {
#pragma unroll
      for (int j = 68; j < 80; ++j) dst[j] = 0u;   // k 136..159 zero pad
    }
  }
  __syncthreads();
  // ---- P3: MFMA  V[128 x 96] = XX[128 x 160] * B'[160 x 96] ----
  const int lane = t & 63, wid = t >> 6;
  const int quad = lane >> 4, l16 = lane & 15;
  const int wm = (wid >> 1) * 64, wn = (wid & 1) * 48;  // wave tile 64 x 48
  f32x4 acc[4][3];
#pragma unroll
  for (int mt = 0; mt < 4; ++mt)
#pragma unroll
    for (int nt = 0; nt < 3; ++nt) acc[mt][nt] = (f32x4){0.f, 0.f, 0.f, 0.f};
#pragma unroll
  for (int ks = 0; ks < 5; ++ks) {
    short8 af[4];
#pragma unroll
    for (int mt = 0; mt < 4; ++mt) {
      const int row = wm + mt * 16 + l16;
      af[mt] = *(const short8*)(smem + XX_OFF + row * KSB + ks * 64 + quad * 16);
    }
#pragma unroll
    for (int nt = 0; nt < 3; ++nt) {
      const int rowb = wn + nt * 16 + l16;
      short8 bfr = *(const short8*)(smem + BT_OFF + rowb * KSB + ks * 64 + quad * 16);
#pragma unroll
      for (int mt = 0; mt < 4; ++mt)
        acc[mt][nt] = __builtin_amdgcn_mfma_f32_16x16x32_bf16(af[mt], bfr, acc[mt][nt], 0, 0, 0);
    }
  }
  __syncthreads();  // MFMA reads done before VT overlays BT
  // ---- P4: stage V^T bf16 [n][c] into LDS (packed b64 writes) ----
  {
    unsigned short* VTb = (unsigned short*)(smem + VT_OFF);
#pragma unroll
    for (int mt = 0; mt < 4; ++mt)
#pragma unroll
      for (int nt = 0; nt < 3; ++nt) {
        const int c0 = wm + mt * 16 + quad * 4;     // D row = m = channel
        const int nl = wn + nt * 16 + l16;          // D col = n
        uint2 w;
        w.x = pack2(acc[mt][nt][0], acc[mt][nt][1]);
        w.y = pack2(acc[mt][nt][2], acc[mt][nt][3]);
        *(uint2*)(VTb + nl * VTS + c0) = w;
      }
  }
  __syncthreads();
  // ---- P5: epilogue (w3/w2/w1 already in registers) ----
  {
    const unsigned short* xr = (const unsigned short*)(smem + X_OFF) + ch * 16;
    short8 x0 = *(const short8*)(xr);
    short8 x1 = *(const short8*)(xr + 8);
    float xf[16];
#pragma unroll
    for (int i = 0; i < 8; ++i) {
      xf[i]     = bf2f((unsigned short)x0[i]);
      xf[i + 8] = bf2f((unsigned short)x1[i]);
    }
    float partial;
    switch (bx * 2 + kh) {
      case 0: partial = epi_dot<0>(smem, ch, xf, w3r, w2r); break;
      case 1: partial = epi_dot<1>(smem, ch, xf, w3r, w2r); break;
      case 2: partial = epi_dot<2>(smem, ch, xf, w3r, w2r); break;
      case 3: partial = epi_dot<3>(smem, ch, xf, w3r, w2r); break;
      case 4: partial = epi_dot<4>(smem, ch, xf, w3r, w2r); break;
      case 5: partial = epi_dot<5>(smem, ch, xf, w3r, w2r); break;
      case 6: partial = epi_dot<6>(smem, ch, xf, w3r, w2r); break;
      default: partial = epi_dot<7>(smem, ch, xf, w3r, w2r); break;
    }
    if (bx == 0 && kh == 0) {  // corr-1 term exactly once per (b,c)
      float S1 = 0.f;
#pragma unroll
      for (int p = 0; p < 16; ++p) S1 += U1[p] * xf[p];
      partial += w1r * S1;
    }
    atomicAdd(&out[(size_t)b * C_CH + ch], partial);
  }
}

extern "C" void kernel_launch(void* const* d_in, const int* in_sizes, int n_in,
                              void* d_out, int out_size, void* d_ws, size_t ws_size,
                              hipStream_t stream) {
  const float* x  = (const float*)d_in[0];
  const float* y  = (const float*)d_in[1];
  const float* U1 = (const float*)d_in[2];
  const float* U2 = (const float*)d_in[3];
  const float* U3 = (const float*)d_in[4];
  const float* W1 = (const float*)d_in[5];
  const float* W2 = (const float*)d_in[6];
  const float* W3 = (const float*)d_in[7];
  float* out = (float*)d_out;
  unsigned short* bt = (unsigned short*)d_ws;
  if (ws_size < (size_t)NCOL * KPAD * sizeof(unsigned short)) return;  // need 122,880 B scratch

  hipMemsetAsync(d_out, 0, (size_t)out_size * sizeof(float), stream);
  build_bt<<<dim3((NCOL * KPAD + 255) / 256), dim3(256), 0, stream>>>(U2, U3, bt);
  mace_main<<<dim3(4, B_ATOMS), dim3(256), 0, stream>>>(x, y, U1, W1, W2, W3, bt, out);
}

// Round 3
// 467.593 us; speedup vs baseline: 1.5432x; 1.0855x over previous
//
#include <hip/hip_runtime.h>
#include <hip/hip_bf16.h>
#include <stdint.h>

// ---- problem constants ----
#define B_ATOMS 8192
#define C_CH    128
#define L_DIM   16
#define E_EL    10
#define NK3     23
#define NK2     4
#define NTRI    136   // 16*17/2 upper-triangle pairs
#define KPAD    160   // K padded to 32-multiple for 16x16x32 MFMA
#define NCOL    384   // 368 (i*23+k3) + 4 (k2) + 1 (U1 col 372) + 11 pad
#define KSB     336   // XX LDS k-stride BYTES (168 bf16; 84 dwords = 20 mod 32 -> <=2-way b128)
#define XTS     132   // XT f32 row stride (x132: 4-aligned for float4, 4 banks/row spread)
#define WTS     132   // wtab f32 row stride

// ---- LDS layout (bytes) ----
#define XX_OFF  0          // 128*336               = 43008
#define XB_OFF  43008      // bf16 [c][16]          =  4096 -> 47104
#define XT_OFF  47104      // f32 [16][132]         =  8448 -> 55552
#define WT_OFF  55552      // f32 [39][132]         = 20592 -> 76144
#define SMEM_BYTES 76144   // x2 = 152288 <= 163840 -> 2 blocks/CU

typedef __attribute__((ext_vector_type(8))) short short8;
typedef __attribute__((ext_vector_type(4))) float f32x4;

struct TriLut { unsigned char p[NTRI]; unsigned char q[NTRI]; };
static constexpr TriLut make_lut() {
  TriLut t{};
  int idx = 0;
  for (int p = 0; p < 16; ++p)
    for (int q = p; q < 16; ++q) { t.p[idx] = (unsigned char)p; t.q[idx] = (unsigned char)q; ++idx; }
  return t;
}
__constant__ TriLut LUT = make_lut();

__device__ __forceinline__ unsigned short f2bf(float f) {
  union { float f; unsigned u; } v; v.f = f;
  unsigned r = v.u + 0x7fffu + ((v.u >> 16) & 1u);   // RNE
  return (unsigned short)(r >> 16);
}
__device__ __forceinline__ unsigned pack2(float a, float b) {
  __hip_bfloat162 h = __float22bfloat162_rn(float2{a, b});   // low half = a
  union { __hip_bfloat162 h; unsigned u; } v; v.h = h;
  return v.u;
}
__device__ __forceinline__ float bf2f(unsigned short h) {
  union { unsigned u; float f; } v; v.u = ((unsigned)h) << 16;
  return v.f;
}

// ---- setup: pack symmetrized B' [n=384][k=160] bf16 into workspace ----
// cols 0..367: U3sym[(i,k3)]; 368..371: U2sym[k2]; 372: U1 in k-rows 136..151.
__global__ void build_bt(const float* __restrict__ U1, const float* __restrict__ U2,
                         const float* __restrict__ U3, unsigned short* __restrict__ bt) {
  int gid = blockIdx.x * 256 + threadIdx.x;
  if (gid >= NCOL * KPAD) return;
  int n  = gid / KPAD;
  int kk = gid - n * KPAD;
  float val = 0.f;
  if (kk < NTRI && n < 372) {
    int p = LUT.p[kk], q = LUT.q[kk];
    if (n < 368) {
      int i = n / NK3, k3 = n - i * NK3;
      val = U3[((p * 16 + q) * 16 + i) * NK3 + k3];
      if (p != q) val += U3[((q * 16 + p) * 16 + i) * NK3 + k3];
    } else {
      int k2 = n - 368;
      val = U2[(p * 16 + q) * NK2 + k2];
      if (p != q) val += U2[(q * 16 + p) * NK2 + k2];
    }
  } else if (n == 372 && kk >= 136 && kk < 152) {
    val = U1[kk - 136];   // pairs with XX k-slots 136..151 = x  ->  V[c,372] = sum_p U1_p x_p
  }
  bt[gid] = f2bf(val);
}

__global__ __launch_bounds__(256, 2) void mace_main(
    const float* __restrict__ x, const float* __restrict__ y,
    const float* __restrict__ W1, const float* __restrict__ W2,
    const float* __restrict__ W3,
    const unsigned short* __restrict__ bt, float* __restrict__ out) {
  __shared__ __align__(16) char smem[SMEM_BYTES];
  const int t  = threadIdx.x;
  const int b  = blockIdx.y;
  const int bx = blockIdx.x;           // n-half: columns [bx*192, bx*192+192)
  const int lane = t & 63, w = t >> 6;
  const int quad = lane >> 4, l16 = lane & 15;
  const int nbase = bx * 192 + w * 48; // wave owns 48 columns

  // ---- P0: B' fragments -> registers (L2-hot gather; issued early, used at P3) ----
  short8 bfrag[3][5];
#pragma unroll
  for (int nt = 0; nt < 3; ++nt) {
    const unsigned short* src = bt + (size_t)(nbase + nt * 16 + l16) * KPAD;
#pragma unroll
    for (int ks = 0; ks < 5; ++ks)
      bfrag[nt][ks] = *(const short8*)(src + ks * 32 + quad * 8);
  }

  // ---- P1: stage x -> Xb (bf16 [c][i]) and XT (f32 [i][c]) ----
  {
    const float4* x4 = (const float4*)(x + (size_t)b * C_CH * L_DIM);
    float* xt = (float*)(smem + XT_OFF);
#pragma unroll
    for (int r = 0; r < 2; ++r) {
      const int o = t + r * 256;
      float4 f = x4[o];
      const int c = o >> 2, i0 = (o & 3) * 4;
      unsigned* xb = (unsigned*)((unsigned short*)(smem + XB_OFF) + c * 16 + i0);
      xb[0] = pack2(f.x, f.y);
      xb[1] = pack2(f.z, f.w);
      xt[(i0 + 0) * XTS + c] = f.x;
      xt[(i0 + 1) * XTS + c] = f.y;
      xt[(i0 + 2) * XTS + c] = f.z;
      xt[(i0 + 3) * XTS + c] = f.w;
    }
  }
  // ---- P1b: combined weights -> wtab[k][c] (k: 0..22 w3, 23..26 w2, 27 w1, 28..38 zero) ----
  {
    float yv[E_EL];
#pragma unroll
    for (int e = 0; e < E_EL; ++e) yv[e] = y[(size_t)b * E_EL + e];  // wave-uniform -> s_load
    float* wt = (float*)(smem + WT_OFF);
    for (int u = t; u < 39 * 32; u += 256) {
      const int k = u >> 5, cg = (u & 31) * 4;
      float4 a = {0.f, 0.f, 0.f, 0.f};
      if (k < 23) {
#pragma unroll
        for (int e = 0; e < E_EL; ++e) {
          float4 wv = *(const float4*)(W3 + (e * NK3 + k) * C_CH + cg);
          a.x += yv[e] * wv.x; a.y += yv[e] * wv.y; a.z += yv[e] * wv.z; a.w += yv[e] * wv.w;
        }
      } else if (k < 27) {
#pragma unroll
        for (int e = 0; e < E_EL; ++e) {
          float4 wv = *(const float4*)(W2 + (e * NK2 + (k - 23)) * C_CH + cg);
          a.x += yv[e] * wv.x; a.y += yv[e] * wv.y; a.z += yv[e] * wv.z; a.w += yv[e] * wv.w;
        }
      } else if (k == 27) {
#pragma unroll
        for (int e = 0; e < E_EL; ++e) {
          float4 wv = *(const float4*)(W1 + e * C_CH + cg);
          a.x += yv[e] * wv.x; a.y += yv[e] * wv.y; a.z += yv[e] * wv.z; a.w += yv[e] * wv.w;
        }
      }
      *(float4*)(wt + k * WTS + cg) = a;
    }
  }
  __syncthreads();
  // ---- P2: XX[c, 0..135] = x_p*x_q bf16; slots 136..151 = x (corr-1 rows); 152..159 = 0 ----
  {
    const int c = t >> 1, half = t & 1;
    const unsigned short* xr = (const unsigned short*)(smem + XB_OFF) + c * 16;
    short8 x0 = *(const short8*)(xr);
    short8 x1 = *(const short8*)(xr + 8);
    float xf[16];
#pragma unroll
    for (int i = 0; i < 8; ++i) {
      xf[i]     = bf2f((unsigned short)x0[i]);
      xf[i + 8] = bf2f((unsigned short)x1[i]);
    }
    unsigned* dst = (unsigned*)(smem + XX_OFF + c * KSB);
    float prev = 0.f;
    int idx = 0;
#pragma unroll
    for (int p = 0; p < 16; ++p) {
#pragma unroll
      for (int q = p; q < 16; ++q) {
        const bool mine = (idx < 68) == (half == 0);
        if (mine) {
          const float val = xf[p] * xf[q];
          if (idx & 1) dst[idx >> 1] = pack2(prev, val);
          else prev = val;
        }
        ++idx;
      }
    }
    if (half) {
      const unsigned* xp = (const unsigned*)xr;  // already-packed bf16 pairs, low = even i
#pragma unroll
      for (int j = 0; j < 8; ++j) dst[68 + j] = xp[j];   // k 136..151 = x
#pragma unroll
      for (int j = 76; j < 80; ++j) dst[j] = 0u;         // k 152..159 = 0
    }
  }
  __syncthreads();
  // ---- P3: MFMA  V[128 x 48/wave] = XX[128 x 160] * B'[160 x 48] (B' in regs) ----
  f32x4 acc[8][3];
#pragma unroll
  for (int mt = 0; mt < 8; ++mt)
#pragma unroll
    for (int nt = 0; nt < 3; ++nt) acc[mt][nt] = (f32x4){0.f, 0.f, 0.f, 0.f};
#pragma unroll
  for (int ks = 0; ks < 5; ++ks) {
    short8 af[8];
#pragma unroll
    for (int mt = 0; mt < 8; ++mt) {
      const int row = mt * 16 + l16;
      af[mt] = *(const short8*)(smem + XX_OFF + row * KSB + ks * 64 + quad * 16);
    }
#pragma unroll
    for (int nt = 0; nt < 3; ++nt)
#pragma unroll
      for (int mt = 0; mt < 8; ++mt)
        acc[mt][nt] = __builtin_amdgcn_mfma_f32_16x16x32_bf16(af[mt], bfrag[nt][ks], acc[mt][nt], 0, 0, 0);
  }
  // ---- P4: register epilogue (no barrier needed: XT/wtab stable since sync1) ----
  {
    int ktab[3], irow[3];
    bool ux[3];
#pragma unroll
    for (int nt = 0; nt < 3; ++nt) {
      const int n = nbase + nt * 16 + l16;
      ux[nt] = (n < 368);
      const int i = n / NK3;
      irow[nt] = ux[nt] ? i : 0;
      ktab[nt] = ux[nt] ? (n - i * NK3) : (n - 345);  // 368..372 -> 23..27; 373..383 -> zero rows
    }
    const float* xt = (const float*)(smem + XT_OFF);
    const float* wt = (const float*)(smem + WT_OFF);
#pragma unroll
    for (int mt = 0; mt < 8; ++mt) {
      const int c4 = mt * 16 + quad * 4;
      float s0 = 0.f, s1 = 0.f, s2 = 0.f, s3 = 0.f;
#pragma unroll
      for (int nt = 0; nt < 3; ++nt) {
        float4 wv = *(const float4*)(wt + ktab[nt] * WTS + c4);
        float4 xv = *(const float4*)(xt + irow[nt] * XTS + c4);
        const float f0 = ux[nt] ? xv.x : 1.f;
        const float f1 = ux[nt] ? xv.y : 1.f;
        const float f2 = ux[nt] ? xv.z : 1.f;
        const float f3 = ux[nt] ? xv.w : 1.f;
        s0 += acc[mt][nt][0] * wv.x * f0;
        s1 += acc[mt][nt][1] * wv.y * f1;
        s2 += acc[mt][nt][2] * wv.z * f2;
        s3 += acc[mt][nt][3] * wv.w * f3;
      }
#pragma unroll
      for (int m = 1; m <= 8; m <<= 1) {
        s0 += __shfl_xor(s0, m, 64);
        s1 += __shfl_xor(s1, m, 64);
        s2 += __shfl_xor(s2, m, 64);
        s3 += __shfl_xor(s3, m, 64);
      }
      if (l16 == 0) {
        float* o = out + (size_t)b * C_CH + c4;
        atomicAdd(o + 0, s0);
        atomicAdd(o + 1, s1);
        atomicAdd(o + 2, s2);
        atomicAdd(o + 3, s3);
      }
    }
  }
}

extern "C" void kernel_launch(void* const* d_in, const int* in_sizes, int n_in,
                              void* d_out, int out_size, void* d_ws, size_t ws_size,
                              hipStream_t stream) {
  const float* x  = (const float*)d_in[0];
  const float* y  = (const float*)d_in[1];
  const float* U1 = (const float*)d_in[2];
  const float* U2 = (const float*)d_in[3];
  const float* U3 = (const float*)d_in[4];
  const float* W1 = (const float*)d_in[5];
  const float* W2 = (const float*)d_in[6];
  const float* W3 = (const float*)d_in[7];
  float* out = (float*)d_out;
  unsigned short* bt = (unsigned short*)d_ws;
  if (ws_size < (size_t)NCOL * KPAD * sizeof(unsigned short)) return;  // need 122,880 B scratch

  hipMemsetAsync(d_out, 0, (size_t)out_size * sizeof(float), stream);
  build_bt<<<dim3((NCOL * KPAD + 255) / 256), dim3(256), 0, stream>>>(U1, U2, U3, bt);
  mace_main<<<dim3(2, B_ATOMS), dim3(256), 0, stream>>>(x, y, W1, W2, W3, bt, out);
}